// Round 3
// baseline (164.445 us; speedup 1.0000x reference)
//
#include <hip/hip_runtime.h>
#include <hip/hip_bf16.h>
#include <stdint.h>

// out[b,t,o] = bias[o] + sum_{c<7,m<8,h<3} W[o, c*8+m, h] * Z[b, c*8+m, (t+h-1)&2047]
// Z[b, cm, s] = (s >= 168) ? x[b, s-24m, c] : 0
//
// k'-reordered fused design: GEMM K-dim uses k' = m*8 + c (A and B agree, so
// the permutation is free). A lane's 8-element B-fragment (k' = kc*32+quad*8+j)
// is then m = kc*4+quad fixed, c = j = 0..6(+pad) -> ONE x row, contiguous:
//   frag = bf16( x[b, ttw-24m, 0..6], 0 ),  ttw = (t0+lb-1)&2047.
// LDS = raw bf16 x rows (7 shorts + pad, 16B stride): one aligned ds_read_b128
// per fragment at local row lb+168-24m (no modulo, no transpose).
// MASKING (round-2 bug fix): ttw < 168 happens for output rows t <= 168 and
// for the t=2047 wrap (h=2) -> t-blocks {0, 128, 1920} take the masked path
// (edge = t0 <= 168 || t0 == SEQ-BT); the other 13/16 blocks have zero mask VALU.
// A-operand = Wf pre-swizzled to the same k' order (direct global loads, L2).
// C/D regs hold 4 consecutive o -> dwordx4 stores (full 64B lines per instr).

#define TAO    24
#define MTAPS  7
#define C_IN   7
#define SEQ    2048
#define DMODEL 512
#define NROWS  65536   // 32*2048
#define BO     128     // o per block
#define BT     128     // t per block
#define XROWS  298     // staged x rows: t0-169 .. t0+128
#define XLD    8       // shorts per staged row (7 + zero pad), 16B

typedef __attribute__((ext_vector_type(8))) short frag_ab;  // 8 bf16
typedef __attribute__((ext_vector_type(4))) float frag_cd;  // 4 fp32

// ---------------- prep: fragment-swizzled W in k' = m*8+c order ----------------
// Wf[((h*32+oc)*2+kc)*64 + lane][j] = W[o*168 + (c*8+m)*3 + h],
//   o = oc*16 + (lane&15), k' = kc*32 + (lane>>4)*8 + j, m = k'>>3, c = k'&7,
//   zero for c == 7 (pad channel).
__global__ __launch_bounds__(256)
void prep_w_kernel(const float* __restrict__ W, __hip_bfloat16* __restrict__ Wf)
{
    const int idx  = blockIdx.x * 256 + threadIdx.x;   // [0, 12288)
    const int lane = idx & 63;
    const int kc   = (idx >> 6) & 1;
    const int oc   = (idx >> 7) & 31;
    const int h    = idx >> 12;
    const int o    = oc * 16 + (lane & 15);
    const int kof  = kc * 32 + (lane >> 4) * 8;

    union { __hip_bfloat16 s[8]; int4 v; } u;
#pragma unroll
    for (int j = 0; j < 8; j++) {
        const int kp = kof + j;
        const int m  = kp >> 3;
        const int c  = kp & 7;
        float v = (c < 7) ? W[o * 168 + (c * 8 + m) * 3 + h] : 0.0f;
        u.s[j] = __float2bfloat16(v);
    }
    ((int4*)Wf)[idx] = u.v;
}

// ---------------- fused GEMM ----------------
__global__ __launch_bounds__(256, 4)
void gemm_kernel(const float* __restrict__ x,
                 const __hip_bfloat16* __restrict__ Wf,
                 const float* __restrict__ bias,
                 float* __restrict__ out)
{
    // raw x rows as bf16: row r (local), channels 0..6 + zero pad. 4864 B.
    __shared__ __align__(16) short xt[304 * XLD];

    const int tid = threadIdx.x;
    const int bo  = blockIdx.x & 3;      // 4 o-blocks
    const int mb  = blockIdx.x >> 2;     // 512 t-blocks
    const int b   = mb >> 4;
    const int t0  = (mb & 15) * BT;
    const int o0  = bo * BO;

    // --- stage x window: rows (t0-169+r)&2047, r in [0,298). One row/thread,
    // 7 coalesced scalar loads (L1 absorbs the stride-28B overlap) + b128 write.
    {
        const float* xb = x + b * (SEQ * C_IN);
        const int base = (t0 - 169 + SEQ) & (SEQ - 1);
#pragma unroll
        for (int it = 0; it < 2; it++) {
            const int r = it * 256 + tid;
            if (r < XROWS) {
                const int xrow = (base + r) & (SEQ - 1);
                const float* p = xb + xrow * C_IN;
                union { short s[8]; int4 v; } u;
#pragma unroll
                for (int c = 0; c < 7; c++) {
                    __hip_bfloat16 bv = __float2bfloat16(p[c]);
                    u.s[c] = *reinterpret_cast<short*>(&bv);
                }
                u.s[7] = 0;
                *(int4*)&xt[r * XLD] = u.v;
            }
        }
    }

    // --- wave geometry; waves 2(o) x 2(t); wave tile 64 o x 64 t
    const int wave = tid >> 6;
    const int lane = tid & 63;
    const int wo   = (wave >> 1) * 64;
    const int wt   = (wave & 1) * 64;
    const int l15  = lane & 15;
    const int quad = lane >> 4;

    frag_cd acc[4][4];
#pragma unroll
    for (int i = 0; i < 4; i++)
#pragma unroll
        for (int j = 0; j < 4; j++)
            acc[i][j] = (frag_cd){0.f, 0.f, 0.f, 0.f};

    __syncthreads();

    // blocks whose fragments can hit ttw < 168 (incl. the t=2047 wrap):
    // t <= 168 spans t0 in {0, 128}; the wrap hits t0 = SEQ-BT.  [round-2 fix]
    const bool edge = (t0 <= MTAPS * TAO) || (t0 == (SEQ - BT));
    const int octile = bo * 8 + (wo >> 4);   // o-chunk base (units of 16 o)

#pragma unroll
    for (int h = 0; h < 3; h++) {
#pragma unroll
        for (int kc = 0; kc < 2; kc++) {
            const int m = kc * 4 + quad;             // tap index for this lane
            frag_ab wfr[4];
#pragma unroll
            for (int mi = 0; mi < 4; mi++) {
                const int tile = (h * 32 + octile + mi) * 2 + kc;
                wfr[mi] = *(const frag_ab*)((const char*)Wf + (size_t)tile * 1024 + lane * 16);
            }
            // --- B fragments: one aligned b128 read each; no mask VALU in
            // the common case. local row = lb + 168 - 24m, lb = wt+ni*16+l15+h.
            const short* gp = &xt[(wt + l15 + h + 168 - 24 * m) * XLD];
            union { frag_ab f; int4 i4; } g[4];
#pragma unroll
            for (int ni = 0; ni < 4; ni++)
                g[ni].f = *(const frag_ab*)(gp + ni * 16 * XLD);  // +256B imm
            if (edge) {
#pragma unroll
                for (int ni = 0; ni < 4; ni++) {
                    const int lb  = wt + ni * 16 + l15 + h;
                    const int ttw = (t0 + lb - 1 + SEQ) & (SEQ - 1);
                    const bool valid = (ttw >= MTAPS * TAO);
                    g[ni].i4.x = valid ? g[ni].i4.x : 0;
                    g[ni].i4.y = valid ? g[ni].i4.y : 0;
                    g[ni].i4.z = valid ? g[ni].i4.z : 0;
                    g[ni].i4.w = valid ? g[ni].i4.w : 0;
                }
            }
#pragma unroll
            for (int mi = 0; mi < 4; mi++)
#pragma unroll
                for (int ni = 0; ni < 4; ni++)
                    acc[mi][ni] = __builtin_amdgcn_mfma_f32_16x16x32_bf16(
                        wfr[mi], g[ni].f, acc[mi][ni], 0, 0, 0);
        }
    }

    // --- epilogue: C/D col = lane&15 = t, row = quad*4+reg = o -> dwordx4
    float4 bias4[4];
#pragma unroll
    for (int mi = 0; mi < 4; mi++)
        bias4[mi] = *(const float4*)&bias[o0 + wo + mi * 16 + quad * 4];

    const size_t rowbase = (size_t)b * SEQ + t0 + wt;
#pragma unroll
    for (int ni = 0; ni < 4; ni++) {
        const size_t r = rowbase + ni * 16 + l15;
        float* orow = out + r * DMODEL + o0 + wo + quad * 4;
#pragma unroll
        for (int mi = 0; mi < 4; mi++) {
            float4 v;
            v.x = acc[mi][ni][0] + bias4[mi].x;
            v.y = acc[mi][ni][1] + bias4[mi].y;
            v.z = acc[mi][ni][2] + bias4[mi].z;
            v.w = acc[mi][ni][3] + bias4[mi].w;
            *(float4*)(orow + mi * 16) = v;
        }
    }
}

// ---------------- fallback (round-1, known-correct, no ws) ----------------
#define KDIM  168
#define KPAD  192
#define FLDK  200
__global__ __launch_bounds__(256, 1)
void fused_tokenconv_kernel(const float* __restrict__ x,
                            const float* __restrict__ W,
                            const float* __restrict__ bias,
                            float* __restrict__ out)
{
    __shared__ __hip_bfloat16 As[128][FLDK];
    __shared__ __hip_bfloat16 Bs[128][FLDK];
    const int tid = threadIdx.x;
    const int blk = blockIdx.x;
    const int nb  = blk & 3;
    const int mb  = blk >> 2;
    const int b   = mb >> 4;
    const int t0  = (mb & 15) * 128;
    const int o0  = nb * 128;
    const float* xb = x + b * (SEQ * C_IN);

    for (int idx = tid; idx < 128 * KPAD; idx += 256) {
        int o_l = idx / KPAD;
        int i   = idx - o_l * KPAD;
        float v = (i < KDIM) ? W[(o0 + o_l) * KDIM + i] : 0.0f;
        Bs[o_l][i] = __float2bfloat16(v);
    }
    for (int idx = tid; idx < 128 * KPAD; idx += 256) {
        int t_l = idx / KPAD;
        int i   = idx - t_l * KPAD;
        float v = 0.0f;
        if (i < KDIM) {
            int c = i / 24;
            int r = i - c * 24;
            int m = r / 3;
            int h = r - m * 3;
            int s = (t0 + t_l + h - 1 + SEQ) & (SEQ - 1);
            if (s >= MTAPS * TAO) v = xb[(s - TAO * m) * C_IN + c];
        }
        As[t_l][i] = __float2bfloat16(v);
    }
    __syncthreads();

    const int wave = tid >> 6;
    const int lane = tid & 63;
    const int wm   = (wave >> 1) * 64;
    const int wn   = (wave & 1) * 64;
    const int l15  = lane & 15;
    const int quad = lane >> 4;

    frag_cd acc[4][4];
#pragma unroll
    for (int i = 0; i < 4; i++)
#pragma unroll
        for (int j = 0; j < 4; j++)
            acc[i][j] = (frag_cd){0.f, 0.f, 0.f, 0.f};

#pragma unroll
    for (int kc = 0; kc < KPAD / 32; kc++) {
        const int kof = kc * 32 + quad * 8;
        frag_ab a[4], bf[4];
#pragma unroll
        for (int mi = 0; mi < 4; mi++)
            a[mi] = *(const frag_ab*)&As[wm + mi * 16 + l15][kof];
#pragma unroll
        for (int ni = 0; ni < 4; ni++)
            bf[ni] = *(const frag_ab*)&Bs[wn + ni * 16 + l15][kof];
#pragma unroll
        for (int mi = 0; mi < 4; mi++)
#pragma unroll
            for (int ni = 0; ni < 4; ni++)
                acc[mi][ni] = __builtin_amdgcn_mfma_f32_16x16x32_bf16(
                    a[mi], bf[ni], acc[mi][ni], 0, 0, 0);
    }
    float* outb = out + (size_t)b * SEQ * DMODEL;
#pragma unroll
    for (int ni = 0; ni < 4; ni++) {
        const int o  = o0 + wn + ni * 16 + l15;
        const float bvv = bias[o];
#pragma unroll
        for (int mi = 0; mi < 4; mi++) {
#pragma unroll
            for (int reg = 0; reg < 4; reg++) {
                const int t = t0 + wm + mi * 16 + quad * 4 + reg;
                outb[(size_t)t * DMODEL + o] = acc[mi][ni][reg] + bvv;
            }
        }
    }
}

extern "C" void kernel_launch(void* const* d_in, const int* in_sizes, int n_in,
                              void* d_out, int out_size, void* d_ws, size_t ws_size,
                              hipStream_t stream) {
    const float* x    = (const float*)d_in[0];   // (32, 2048, 7) fp32
    const float* W    = (const float*)d_in[1];   // (512, 56, 3) fp32
    const float* bias = (const float*)d_in[2];   // (512,) fp32
    float* out        = (float*)d_out;           // (32, 2048, 512) fp32

    const size_t w_bytes = (size_t)12288 * 16;   // 196,608
    if (ws_size >= w_bytes) {
        __hip_bfloat16* Wf = (__hip_bfloat16*)d_ws;
        hipLaunchKernelGGL(prep_w_kernel, dim3(48), dim3(256), 0, stream, W, Wf);
        hipLaunchKernelGGL(gemm_kernel, dim3((DMODEL / BO) * (NROWS / BT)), dim3(256), 0, stream,
                           x, Wf, bias, out);
    } else {
        hipLaunchKernelGGL(fused_tokenconv_kernel, dim3(32 * 16 * 4), dim3(256), 0, stream,
                           x, W, bias, out);
    }
}

// Round 5
// 148.926 us; speedup vs baseline: 1.1042x; 1.1042x over previous
//
#include <hip/hip_runtime.h>
#include <hip/hip_bf16.h>
#include <stdint.h>

// out[b,t,o] = bias[o] + sum_{c<7,m<8,h<3} W[o, c*8+m, h] * Z[b, c*8+m, (t+h-1)&2047]
// Z[b, cm, s] = (s >= 168) ? x[b, s-24m, c] : 0
//
// k'-reordered fused design (r2): GEMM K-dim uses k' = m*8 + c. A lane's
// 8-element B-fragment (k' = kc*32+quad*8+j) has m = kc*4+quad fixed,
// c = j -> ONE contiguous x row: frag = bf16(x[b, ttw-24m, 0..6], 0).
// LDS xt = raw bf16 x rows (7 shorts + pad): one aligned ds_read_b128 per
// fragment at local row lb+168-24m. Masking only in t-blocks {0,128,1920}
// (edge = t0 <= 168 || t0 == SEQ-BT)  [round-2 fix].
//
// NEW (r4): LDS-transposed epilogue. Direct stores were 16 x 64B segments
// per instruction (l15->row stride 2KB); suspected write-path bottleneck.
// Now: stage 64t x 128o half-tiles into padded obuf (stride 136 floats,
// <=4-way bank aliasing), then stream linearly: 1KB per store instruction
// in two 512B segments. Reverted to __launch_bounds__(256,3) (r3's (256,4)
// likely forced VGPR spills).

#define TAO    24
#define MTAPS  7
#define C_IN   7
#define SEQ    2048
#define DMODEL 512
#define NROWS  65536   // 32*2048
#define BO     128     // o per block
#define BT     128     // t per block
#define XROWS  298     // staged x rows: t0-169 .. t0+128
#define XLD    8       // shorts per staged row (7 + zero pad), 16B
#define OSTRIDE 136    // obuf row stride in floats (128 + 8 pad)

typedef __attribute__((ext_vector_type(8))) short frag_ab;  // 8 bf16
typedef __attribute__((ext_vector_type(4))) float frag_cd;  // 4 fp32

// ---------------- prep: fragment-swizzled W in k' = m*8+c order ----------------
// Wf[((h*32+oc)*2+kc)*64 + lane][j] = W[o*168 + (c*8+m)*3 + h],
//   o = oc*16 + (lane&15), k' = kc*32 + (lane>>4)*8 + j, m = k'>>3, c = k'&7,
//   zero for c == 7 (pad channel).
__global__ __launch_bounds__(256)
void prep_w_kernel(const float* __restrict__ W, __hip_bfloat16* __restrict__ Wf)
{
    const int idx  = blockIdx.x * 256 + threadIdx.x;   // [0, 12288)
    const int lane = idx & 63;
    const int kc   = (idx >> 6) & 1;
    const int oc   = (idx >> 7) & 31;
    const int h    = idx >> 12;
    const int o    = oc * 16 + (lane & 15);
    const int kof  = kc * 32 + (lane >> 4) * 8;

    union { __hip_bfloat16 s[8]; int4 v; } u;
#pragma unroll
    for (int j = 0; j < 8; j++) {
        const int kp = kof + j;
        const int m  = kp >> 3;
        const int c  = kp & 7;
        float v = (c < 7) ? W[o * 168 + (c * 8 + m) * 3 + h] : 0.0f;
        u.s[j] = __float2bfloat16(v);
    }
    ((int4*)Wf)[idx] = u.v;
}

// ---------------- fused GEMM ----------------
__global__ __launch_bounds__(256, 3)
void gemm_kernel(const float* __restrict__ x,
                 const __hip_bfloat16* __restrict__ Wf,
                 const float* __restrict__ bias,
                 float* __restrict__ out)
{
    // raw x rows as bf16: row r (local), channels 0..6 + zero pad. 4864 B.
    __shared__ __align__(16) short xt[304 * XLD];
    // output staging: 64 t-rows x 128 o, padded. 34816 B. total LDS 39.7 KB.
    __shared__ __align__(16) float obuf[64 * OSTRIDE];

    const int tid = threadIdx.x;
    const int bo  = blockIdx.x & 3;      // 4 o-blocks
    const int mb  = blockIdx.x >> 2;     // 512 t-blocks
    const int b   = mb >> 4;
    const int t0  = (mb & 15) * BT;
    const int o0  = bo * BO;

    // --- stage x window: rows (t0-169+r)&2047, r in [0,298). One row/thread,
    // 7 coalesced scalar loads (L1 absorbs the stride-28B overlap) + b128 write.
    {
        const float* xb = x + b * (SEQ * C_IN);
        const int base = (t0 - 169 + SEQ) & (SEQ - 1);
#pragma unroll
        for (int it = 0; it < 2; it++) {
            const int r = it * 256 + tid;
            if (r < XROWS) {
                const int xrow = (base + r) & (SEQ - 1);
                const float* p = xb + xrow * C_IN;
                union { short s[8]; int4 v; } u;
#pragma unroll
                for (int c = 0; c < 7; c++) {
                    __hip_bfloat16 bv = __float2bfloat16(p[c]);
                    u.s[c] = *reinterpret_cast<short*>(&bv);
                }
                u.s[7] = 0;
                *(int4*)&xt[r * XLD] = u.v;
            }
        }
    }

    // --- wave geometry; waves 2(o) x 2(t); wave tile 64 o x 64 t
    const int wave = tid >> 6;
    const int lane = tid & 63;
    const int wo   = (wave >> 1) * 64;
    const int wt   = (wave & 1) * 64;
    const int l15  = lane & 15;
    const int quad = lane >> 4;

    frag_cd acc[4][4];
#pragma unroll
    for (int i = 0; i < 4; i++)
#pragma unroll
        for (int j = 0; j < 4; j++)
            acc[i][j] = (frag_cd){0.f, 0.f, 0.f, 0.f};

    __syncthreads();

    // blocks whose fragments can hit ttw < 168 (incl. the t=2047 wrap):
    // t <= 168 spans t0 in {0, 128}; the wrap hits t0 = SEQ-BT.  [round-2 fix]
    const bool edge = (t0 <= MTAPS * TAO) || (t0 == (SEQ - BT));
    const int octile = bo * 8 + (wo >> 4);   // o-chunk base (units of 16 o)

#pragma unroll
    for (int h = 0; h < 3; h++) {
#pragma unroll
        for (int kc = 0; kc < 2; kc++) {
            const int m = kc * 4 + quad;             // tap index for this lane
            frag_ab wfr[4];
#pragma unroll
            for (int mi = 0; mi < 4; mi++) {
                const int tile = (h * 32 + octile + mi) * 2 + kc;
                wfr[mi] = *(const frag_ab*)((const char*)Wf + (size_t)tile * 1024 + lane * 16);
            }
            // --- B fragments: one aligned b128 read each; no mask VALU in
            // the common case. local row = lb + 168 - 24m, lb = wt+ni*16+l15+h.
            const short* gp = &xt[(wt + l15 + h + 168 - 24 * m) * XLD];
            union { frag_ab f; int4 i4; } g[4];
#pragma unroll
            for (int ni = 0; ni < 4; ni++)
                g[ni].f = *(const frag_ab*)(gp + ni * 16 * XLD);  // +256B imm
            if (edge) {
#pragma unroll
                for (int ni = 0; ni < 4; ni++) {
                    const int lb  = wt + ni * 16 + l15 + h;
                    const int ttw = (t0 + lb - 1 + SEQ) & (SEQ - 1);
                    const bool valid = (ttw >= MTAPS * TAO);
                    g[ni].i4.x = valid ? g[ni].i4.x : 0;
                    g[ni].i4.y = valid ? g[ni].i4.y : 0;
                    g[ni].i4.z = valid ? g[ni].i4.z : 0;
                    g[ni].i4.w = valid ? g[ni].i4.w : 0;
                }
            }
#pragma unroll
            for (int mi = 0; mi < 4; mi++)
#pragma unroll
                for (int ni = 0; ni < 4; ni++)
                    acc[mi][ni] = __builtin_amdgcn_mfma_f32_16x16x32_bf16(
                        wfr[mi], g[ni].f, acc[mi][ni], 0, 0, 0);
        }
    }

    // --- epilogue: C/D col = l15 = t, row = quad*4+reg = o.
    // Stage each 64-t half into obuf, then stream out linearly (1KB/instr).
    float4 bias4[4];
#pragma unroll
    for (int mi = 0; mi < 4; mi++)
        bias4[mi] = *(const float4*)&bias[o0 + wo + mi * 16 + quad * 4];

    const int wthalf = wt >> 6;          // which t-half this wave's acc covers
#pragma unroll
    for (int half = 0; half < 2; half++) {
        if (wthalf == half) {
#pragma unroll
            for (int ni = 0; ni < 4; ni++) {
                float* orow = &obuf[(ni * 16 + l15) * OSTRIDE + wo + quad * 4];
#pragma unroll
                for (int mi = 0; mi < 4; mi++) {
                    float4 v;
                    v.x = acc[mi][ni][0] + bias4[mi].x;
                    v.y = acc[mi][ni][1] + bias4[mi].y;
                    v.z = acc[mi][ni][2] + bias4[mi].z;
                    v.w = acc[mi][ni][3] + bias4[mi].w;
                    *(float4*)(orow + mi * 16) = v;
                }
            }
        }
        __syncthreads();
        // cooperative linear store: 64 rows x 512B slice; per instruction
        // 64 lanes = 1KB = two full 512B row-slices.
        const size_t gbase = (size_t)b * SEQ * DMODEL
                           + (size_t)(t0 + half * 64) * DMODEL + o0;
#pragma unroll
        for (int it = 0; it < 8; it++) {
            const int L  = (it * 256 + tid) * 4;   // float index in half tile
            const int tl = L >> 7;                 // /128 floats per row slice
            const int ol = L & 127;
            const float4 v = *(const float4*)&obuf[tl * OSTRIDE + ol];
            *(float4*)(out + gbase + (size_t)tl * DMODEL + ol) = v;
        }
        if (half == 0) __syncthreads();   // obuf reused by half 1
    }
}

// ---------------- fallback (round-1, known-correct, no ws) ----------------
#define KDIM  168
#define KPAD  192
#define FLDK  200
__global__ __launch_bounds__(256, 1)
void fused_tokenconv_kernel(const float* __restrict__ x,
                            const float* __restrict__ W,
                            const float* __restrict__ bias,
                            float* __restrict__ out)
{
    __shared__ __hip_bfloat16 As[128][FLDK];
    __shared__ __hip_bfloat16 Bs[128][FLDK];
    const int tid = threadIdx.x;
    const int blk = blockIdx.x;
    const int nb  = blk & 3;
    const int mb  = blk >> 2;
    const int b   = mb >> 4;
    const int t0  = (mb & 15) * 128;
    const int o0  = nb * 128;
    const float* xb = x + b * (SEQ * C_IN);

    for (int idx = tid; idx < 128 * KPAD; idx += 256) {
        int o_l = idx / KPAD;
        int i   = idx - o_l * KPAD;
        float v = (i < KDIM) ? W[(o0 + o_l) * KDIM + i] : 0.0f;
        Bs[o_l][i] = __float2bfloat16(v);
    }
    for (int idx = tid; idx < 128 * KPAD; idx += 256) {
        int t_l = idx / KPAD;
        int i   = idx - t_l * KPAD;
        float v = 0.0f;
        if (i < KDIM) {
            int c = i / 24;
            int r = i - c * 24;
            int m = r / 3;
            int h = r - m * 3;
            int s = (t0 + t_l + h - 1 + SEQ) & (SEQ - 1);
            if (s >= MTAPS * TAO) v = xb[(s - TAO * m) * C_IN + c];
        }
        As[t_l][i] = __float2bfloat16(v);
    }
    __syncthreads();

    const int wave = tid >> 6;
    const int lane = tid & 63;
    const int wm   = (wave >> 1) * 64;
    const int wn   = (wave & 1) * 64;
    const int l15  = lane & 15;
    const int quad = lane >> 4;

    frag_cd acc[4][4];
#pragma unroll
    for (int i = 0; i < 4; i++)
#pragma unroll
        for (int j = 0; j < 4; j++)
            acc[i][j] = (frag_cd){0.f, 0.f, 0.f, 0.f};

#pragma unroll
    for (int kc = 0; kc < KPAD / 32; kc++) {
        const int kof = kc * 32 + quad * 8;
        frag_ab a[4], bf[4];
#pragma unroll
        for (int mi = 0; mi < 4; mi++)
            a[mi] = *(const frag_ab*)&As[wm + mi * 16 + l15][kof];
#pragma unroll
        for (int ni = 0; ni < 4; ni++)
            bf[ni] = *(const frag_ab*)&Bs[wn + ni * 16 + l15][kof];
#pragma unroll
        for (int mi = 0; mi < 4; mi++)
#pragma unroll
            for (int ni = 0; ni < 4; ni++)
                acc[mi][ni] = __builtin_amdgcn_mfma_f32_16x16x32_bf16(
                    a[mi], bf[ni], acc[mi][ni], 0, 0, 0);
    }
    float* outb = out + (size_t)b * SEQ * DMODEL;
#pragma unroll
    for (int ni = 0; ni < 4; ni++) {
        const int o  = o0 + wn + ni * 16 + l15;
        const float bvv = bias[o];
#pragma unroll
        for (int mi = 0; mi < 4; mi++) {
#pragma unroll
            for (int reg = 0; reg < 4; reg++) {
                const int t = t0 + wm + mi * 16 + quad * 4 + reg;
                outb[(size_t)t * DMODEL + o] = acc[mi][ni][reg] + bvv;
            }
        }
    }
}

extern "C" void kernel_launch(void* const* d_in, const int* in_sizes, int n_in,
                              void* d_out, int out_size, void* d_ws, size_t ws_size,
                              hipStream_t stream) {
    const float* x    = (const float*)d_in[0];   // (32, 2048, 7) fp32
    const float* W    = (const float*)d_in[1];   // (512, 56, 3) fp32
    const float* bias = (const float*)d_in[2];   // (512,) fp32
    float* out        = (float*)d_out;           // (32, 2048, 512) fp32

    const size_t w_bytes = (size_t)12288 * 16;   // 196,608
    if (ws_size >= w_bytes) {
        __hip_bfloat16* Wf = (__hip_bfloat16*)d_ws;
        hipLaunchKernelGGL(prep_w_kernel, dim3(48), dim3(256), 0, stream, W, Wf);
        hipLaunchKernelGGL(gemm_kernel, dim3((DMODEL / BO) * (NROWS / BT)), dim3(256), 0, stream,
                           x, Wf, bias, out);
    } else {
        hipLaunchKernelGGL(fused_tokenconv_kernel, dim3(32 * 16 * 4), dim3(256), 0, stream,
                           x, W, bias, out);
    }
}